// Round 6
// baseline (162.122 us; speedup 1.0000x reference)
//
#include <hip/hip_runtime.h>

// QNet forward, MI355X — R6: counted-vmcnt raw-barrier pipeline (T3/T4/T5).
// B=65536 rows, obs=1129 (37 self + 39*28 others).
// 256 thr (4 waves) per block, 128 rows/block (32 rows = 2 rowsets per wave),
// grid 512 -> 2 blocks/CU, 8 waves/CU.
//
// Pass 1 K-loop: triple-buffered LDS staging of W_al fragments via
// global_load_lds; per chunk: [asm vmcnt(6); s_barrier; sched_barrier(0);
// MFMA compute; stage chunk c+2; load A chunk c+2]. Counted vmcnt keeps ~6-12
// vmem ops in flight per wave ACROSS barriers (no vmcnt(0) drain in the loop).
// NB=3 + stage-after-compute makes the buffer overwrite race-free: chunk c+2
// overwrites buf[(c+2)%3] = buf[(c-1)%3], whose readers all completed before
// the barrier we just passed (ds_reads lgkm-complete before MFMA before barrier).
// Uniform 2 glds/wave: waves 2,3 duplicate-stage units 4,5 (identical bytes).
//
// Fragment maps (gfx950 16x16x32 bf16): A/B: row|col = lane&15, k = 8*(lane>>4)+i
//   C/D: col = lane&15, row = 4*(lane>>4) + reg
// Split-bf16: a*b ~= ah*bh + ah*bl + al*bh (3 MFMA; pass-2 others: 2-term).
//
// d_ws: 120 units of 128 bf16x8 (64 hi + 64 lo frags), 2 KB each = 245760 B.
//   W_al: unit = c*3+t (c<36, t<3) | W_self: 108+c*2+t | W_oth: 112+t
//   W_ao: 114+t | W_emb: 116+t | W_out: 118+t

typedef __bf16 bf16x8 __attribute__((ext_vector_type(8)));
typedef float  f32x4  __attribute__((ext_vector_type(4)));

constexpr int OBS = 1129;

#define MFMA(a, b, c) __builtin_amdgcn_mfma_f32_16x16x32_bf16((a), (b), (c), 0, 0, 0)

__device__ __forceinline__ float4 ld4(const float* p) {
    float4 v;
    __builtin_memcpy(&v, p, 16);
    return v;
}

__device__ __forceinline__ void split8(const float* a, bf16x8& h, bf16x8& l) {
#pragma unroll
    for (int i = 0; i < 8; ++i) {
        __bf16 hb = (__bf16)a[i];
        h[i] = hb;
        l[i] = (__bf16)(a[i] - (float)hb);
    }
}

__device__ __forceinline__ f32x4 mm3(bf16x8 ah, bf16x8 al, bf16x8 bh, bf16x8 bl, f32x4 c) {
    c = MFMA(ah, bh, c);
    c = MFMA(ah, bl, c);
    c = MFMA(al, bh, c);
    return c;
}

__device__ __forceinline__ void glds16(const void* g, void* l) {
    __builtin_amdgcn_global_load_lds((const __attribute__((address_space(1))) void*)g,
                                     (__attribute__((address_space(3))) void*)l, 16, 0, 0);
}

// ---------------- prep: split weights into fragment order ----------------
__global__ void prep_weights(const float* __restrict__ W_al,
                             const float* __restrict__ W_self,
                             const float* __restrict__ W_oth,
                             const float* __restrict__ W_ao,
                             const float* __restrict__ W_emb,
                             const float* __restrict__ W_out,
                             bf16x8* __restrict__ ws)
{
    const int u = blockIdx.x;     // 120 units
    const int l = threadIdx.x;    // 64 lanes
    const int s = l >> 4, col = l & 15;
    const float* W; int K, N, ld, c, t;
    if (u < 108)      { c = u / 3;         t = u % 3;         W = W_al;   K = 1129; N = 40; ld = 40; }
    else if (u < 112) { c = (u - 108) / 2; t = (u - 108) & 1; W = W_self; K = 37;   N = 32; ld = 32; }
    else if (u < 114) { c = 0;             t = u - 112;       W = W_oth;  K = 28;   N = 32; ld = 32; }
    else if (u < 116) { c = 0;             t = u - 114;       W = W_ao;   K = 32;   N = 32; ld = 32; }
    else if (u < 118) { c = 0;             t = u - 116;       W = W_emb;  K = 32;   N = 32; ld = 32; }
    else              { c = 0;             t = u - 118;       W = W_out;  K = 32;   N = 21; ld = 21; }
    const int j = t * 16 + col;
    bf16x8 h, lo;
#pragma unroll
    for (int i = 0; i < 8; ++i) {
        int k = c * 32 + s * 8 + i;
        float w = (k < K && j < N) ? W[k * ld + j] : 0.f;
        __bf16 hb = (__bf16)w;
        h[i]  = hb;
        lo[i] = (__bf16)(w - (float)hb);
    }
    ws[u * 128 + l]      = h;
    ws[u * 128 + 64 + l] = lo;
}

// tail chunk 35 loader: k = 1120..1151, valid <= 1128
__device__ __forceinline__ void loadA_tail(const float* __restrict__ orow, int s, float* av) {
#pragma unroll
    for (int i = 0; i < 8; ++i) av[i] = 0.f;
    if (s == 0) {
        float4 p = ld4(orow + 1120), q = ld4(orow + 1124);
        av[0] = p.x; av[1] = p.y; av[2] = p.z; av[3] = p.w;
        av[4] = q.x; av[5] = q.y; av[6] = q.z; av[7] = q.w;
    } else if (s == 1) {
        av[0] = orow[1128];
    }
}

// pass-2 A loader: agent n, k = 0..27 (+4 zero pad on s==3)
__device__ __forceinline__ void loadA2(const float* __restrict__ orow, int s, int n, float* av) {
    const float* op = orow + 37 + n * 28;
    if (s < 3) {
        float4 p = ld4(op + s * 8), q = ld4(op + s * 8 + 4);
        av[0] = p.x; av[1] = p.y; av[2] = p.z; av[3] = p.w;
        av[4] = q.x; av[5] = q.y; av[6] = q.z; av[7] = q.w;
    } else {
        float4 p = ld4(op + 24);
        av[0] = p.x; av[1] = p.y; av[2] = p.z; av[3] = p.w;
        av[4] = 0.f; av[5] = 0.f; av[6] = 0.f; av[7] = 0.f;
    }
}

// ---------------- main kernel: 256 threads (4 waves), 128 rows ----------------
__global__ __launch_bounds__(256, 2)
void qnet_fwd(const float* __restrict__ obs,
              const float* __restrict__ b_al,
              const float* __restrict__ b_ao,
              const float* __restrict__ b_emb,
              const float* __restrict__ b_out,
              const bf16x8* __restrict__ wf,
              float* __restrict__ out)
{
    __shared__ __align__(16) char sB[3][6144];      // B-frag triple buffer
    __shared__ float  sW[4 * 1568];                 // per wave: 2 rowsets x [16][49]
    __shared__ __bf16 sHi[4 * 640], sLo[4 * 640];   // per-wave head exchange [16][40]

    const int t    = threadIdx.x;
    const int lane = t & 63;
    const int wv   = t >> 6;
    const int s    = lane >> 4;
    const int cq   = lane & 15;
    const int rowbase = blockIdx.x * 128 + wv * 32;
    const float* __restrict__ o0 = obs + (size_t)(rowbase + cq) * OBS;
    const float* __restrict__ o1 = o0 + (size_t)16 * OBS;
    const char* __restrict__ wfb = (const char*)wf;
    float* __restrict__ sWw = sW + wv * 1568;
    __bf16* __restrict__ hiw = sHi + wv * 640;
    __bf16* __restrict__ low = sLo + wv * 640;

    const f32x4 zf = {0.f, 0.f, 0.f, 0.f};

    // ================= pass 1: logits = obs @ W_al =================
    f32x4 a0_0 = zf, a0_1 = zf, a0_2 = zf;   // rowset 0 accs (3 col-tiles)
    f32x4 a1_0 = zf, a1_1 = zf, a1_2 = zf;   // rowset 1

    float Aa0[8], Aa1[8], Ab0[8], Ab1[8], Ac0[8], Ac1[8];   // 3 A banks x 2 rowsets

    // uniform 2 glds/wave: waves 0-3 stage unit wv; waves stage unit 4+(wv&1)
    // (waves 2,3 duplicate-write units 4,5 with identical bytes -> benign)
#define STAGE_B(DST, C)                                                           \
    do {                                                                          \
        const char* _src = wfb + (size_t)(C) * 6144;                              \
        glds16(_src + wv * 1024 + lane * 16, (char*)(DST) + wv * 1024);           \
        glds16(_src + (4 + (wv & 1)) * 1024 + lane * 16,                          \
               (char*)(DST) + (4 + (wv & 1)) * 1024);                             \
    } while (0)

#define LOADA(C, R0, R1)                                                          \
    do {                                                                          \
        const int _k = (C) * 32 + s * 8;                                          \
        float4 _p0 = ld4(o0 + _k), _q0 = ld4(o0 + _k + 4);                        \
        float4 _p1 = ld4(o1 + _k), _q1 = ld4(o1 + _k + 4);                        \
        R0[0]=_p0.x; R0[1]=_p0.y; R0[2]=_p0.z; R0[3]=_p0.w;                       \
        R0[4]=_q0.x; R0[5]=_q0.y; R0[6]=_q0.z; R0[7]=_q0.w;                       \
        R1[0]=_p1.x; R1[1]=_p1.y; R1[2]=_p1.z; R1[3]=_p1.w;                       \
        R1[4]=_q1.x; R1[5]=_q1.y; R1[6]=_q1.z; R1[7]=_q1.w;                       \
    } while (0)

#define COMPUTE_CHUNK(BUF, AV0, AV1)                                              \
    do {                                                                          \
        bf16x8 h0, l0, h1, l1;                                                    \
        split8((AV0), h0, l0);                                                    \
        split8((AV1), h1, l1);                                                    \
        const char* _b = (const char*)(BUF);                                      \
        bf16x8 b0h = *(const bf16x8*)(_b + lane * 16);                            \
        bf16x8 b0l = *(const bf16x8*)(_b + 1024 + lane * 16);                     \
        bf16x8 b1h = *(const bf16x8*)(_b + 2048 + lane * 16);                     \
        bf16x8 b1l = *(const bf16x8*)(_b + 3072 + lane * 16);                     \
        bf16x8 b2h = *(const bf16x8*)(_b + 4096 + lane * 16);                     \
        bf16x8 b2l = *(const bf16x8*)(_b + 5120 + lane * 16);                     \
        __builtin_amdgcn_s_setprio(1);                                            \
        a0_0 = mm3(h0, l0, b0h, b0l, a0_0);                                       \
        a0_1 = mm3(h0, l0, b1h, b1l, a0_1);                                       \
        a0_2 = mm3(h0, l0, b2h, b2l, a0_2);                                       \
        a1_0 = mm3(h1, l1, b0h, b0l, a1_0);                                       \
        a1_1 = mm3(h1, l1, b1h, b1l, a1_1);                                       \
        a1_2 = mm3(h1, l1, b2h, b2l, a1_2);                                       \
        __builtin_amdgcn_s_setprio(0);                                            \
    } while (0)

#define PHASE_SYNC()                                                              \
    do {                                                                          \
        asm volatile("s_waitcnt vmcnt(6)" ::: "memory");                          \
        __builtin_amdgcn_s_barrier();                                             \
        __builtin_amdgcn_sched_barrier(0);                                        \
    } while (0)

    // prologue: chunks 0,1 staged/loaded; fence between so chunk-0 ops are
    // strictly older than chunk-1 ops (order-robust vmcnt counting)
    STAGE_B(sB[0], 0);
    LOADA(0, Aa0, Aa1);
    asm volatile("" ::: "memory");
    STAGE_B(sB[1], 1);
    LOADA(1, Ab0, Ab1);

    // steady: chunks 0..32 (all full); body(c) = sync, compute(c), stage c+2
    for (int t3 = 0; t3 < 11; ++t3) {
        const int c = t3 * 3;
        PHASE_SYNC();
        COMPUTE_CHUNK(sB[0], Aa0, Aa1);
        STAGE_B(sB[2], c + 2);
        LOADA(c + 2, Ac0, Ac1);

        PHASE_SYNC();
        COMPUTE_CHUNK(sB[1], Ab0, Ab1);
        STAGE_B(sB[0], c + 3);
        LOADA(c + 3, Aa0, Aa1);

        PHASE_SYNC();
        COMPUTE_CHUNK(sB[2], Ac0, Ac1);
        STAGE_B(sB[1], c + 4);
        LOADA(c + 4, Ab0, Ab1);
    }
    // exit state: computed 0..32; buf0=33 (bankA), buf1=34 (bankB)

    // chunk 33
    PHASE_SYNC();
    COMPUTE_CHUNK(sB[0], Aa0, Aa1);
    STAGE_B(sB[2], 35);                      // 35%3==2; buf2 readers done
    float At0[8], At1[8];
    loadA_tail(o0, s, At0);
    loadA_tail(o1, s, At1);
    // chunks 34, 35 (full drain epilogue — 1 of 36 barriers, negligible)
    __syncthreads();
    COMPUTE_CHUNK(sB[1], Ab0, Ab1);
    COMPUTE_CHUNK(sB[2], At0, At1);

    // ===== softmax over 40 cols (intra-wave; C rows spread: row = 4s+j) =====
    {
        const float bal0 = b_al[cq];
        const float bal1 = b_al[16 + cq];
        const bool  v2m  = (cq < 8);
        const float bal2 = v2m ? b_al[32 + cq] : 0.f;

#define SOFTMAX_RS(A0, A1, A2, SWB)                                               \
    do {                                                                          \
        _Pragma("unroll")                                                         \
        for (int j = 0; j < 4; ++j) {                                             \
            float v0 = A0[j] + bal0, v1 = A1[j] + bal1, vv = A2[j] + bal2;        \
            float m = fmaxf(fmaxf(v0, v1), v2m ? vv : -3.4e38f);                  \
            _Pragma("unroll")                                                     \
            for (int d = 1; d < 16; d <<= 1) m = fmaxf(m, __shfl_xor(m, d));      \
            float e0 = __expf(v0 - m), e1 = __expf(v1 - m);                       \
            float e2 = v2m ? __expf(vv - m) : 0.f;                                \
            float sm = e0 + e1 + e2;                                              \
            _Pragma("unroll")                                                     \
            for (int d = 1; d < 16; d <<= 1) sm += __shfl_xor(sm, d);             \
            float inv = 1.f / sm;                                                 \
            (SWB)[(s * 4 + j) * 49 + cq]      = e0 * inv;                         \
            (SWB)[(s * 4 + j) * 49 + 16 + cq] = e1 * inv;                         \
            if (v2m) (SWB)[(s * 4 + j) * 49 + 32 + cq] = e2 * inv;                \
        }                                                                         \
    } while (0)

        SOFTMAX_RS(a0_0, a0_1, a0_2, sWw);
        SOFTMAX_RS(a1_0, a1_1, a1_2, (sWw + 784));
    }
    // no barrier: sWw is wave-private; LDS ops are wave-ordered

    // ================= pass 2: encodings, weighted sum =================
    float* __restrict__ sw0 = sWw;
    float* __restrict__ sw1 = sWw + 784;
    f32x4 atA0 = zf, atA1 = zf, atB0 = zf, atB1 = zf;

#define SELF_ENC(OROW, SWB, AT0, AT1)                                             \
    do {                                                                          \
        f32x4 e0 = zf, e1 = zf;                                                   \
        {                                                                         \
            float4 p = ld4((OROW) + s * 8), q = ld4((OROW) + s * 8 + 4);          \
            float av[8] = {p.x, p.y, p.z, p.w, q.x, q.y, q.z, q.w};               \
            bf16x8 ah, al; split8(av, ah, al);                                    \
            const bf16x8* bu = wf + (size_t)108 * 128;                            \
            e0 = mm3(ah, al, bu[lane], bu[64 + lane], e0);                        \
            e1 = mm3(ah, al, bu[128 + lane], bu[192 + lane], e1);                 \
        }                                                                         \
        {                                                                         \
            float av[8] = {0, 0, 0, 0, 0, 0, 0, 0};                               \
            if (s == 0) {                                                         \
                float4 p = ld4((OROW) + 32);                                      \
                av[0] = p.x; av[1] = p.y; av[2] = p.z; av[3] = p.w;               \
                av[4] = (OROW)[36];                                               \
            }                                                                     \
            bf16x8 ah, al; split8(av, ah, al);                                    \
            const bf16x8* bu = wf + (size_t)110 * 128;                            \
            e0 = mm3(ah, al, bu[lane], bu[64 + lane], e0);                        \
            e1 = mm3(ah, al, bu[128 + lane], bu[192 + lane], e1);                 \
        }                                                                         \
        _Pragma("unroll")                                                         \
        for (int j = 0; j < 4; ++j) {                                             \
            float w0 = (SWB)[(s * 4 + j) * 49];                                   \
            AT0[j] = w0 * e0[j];                                                  \
            AT1[j] = w0 * e1[j];                                                  \
        }                                                                         \
    } while (0)

    SELF_ENC(o0, sw0, atA0, atA1);
    SELF_ENC(o1, sw1, atB0, atB1);

    // other agents: 2-term (A hi only), W_oth hoisted, 12-load batches
    {
        const bf16x8* bo = wf + (size_t)112 * 128;
        const bf16x8 Boh0 = bo[lane],       Bol0 = bo[64 + lane];
        const bf16x8 Boh1 = bo[128 + lane], Bol1 = bo[192 + lane];

#define PROC_AG(N, AV, SWB, AT0, AT1)                                             \
    do {                                                                          \
        bf16x8 ah;                                                                \
        _Pragma("unroll")                                                         \
        for (int i = 0; i < 8; ++i) ah[i] = (__bf16)(AV)[i];                      \
        f32x4 e0 = MFMA(ah, Boh0, zf); e0 = MFMA(ah, Bol0, e0);                   \
        f32x4 e1 = MFMA(ah, Boh1, zf); e1 = MFMA(ah, Bol1, e1);                   \
        _Pragma("unroll")                                                         \
        for (int j = 0; j < 4; ++j) {                                             \
            float wn = (SWB)[(s * 4 + j) * 49 + 1 + (N)];                         \
            AT0[j] += wn * fmaxf(e0[j], 0.f);                                     \
            AT1[j] += wn * fmaxf(e1[j], 0.f);                                     \
        }                                                                         \
    } while (0)

        for (int g = 0; g < 19; ++g) {
            const int n = g * 2;
            float q00[8], q01[8], q10[8], q11[8];
            loadA2(o0, s, n,     q00);
            loadA2(o1, s, n,     q01);
            loadA2(o0, s, n + 1, q10);
            loadA2(o1, s, n + 1, q11);
            PROC_AG(n,     q00, sw0, atA0, atA1);
            PROC_AG(n,     q01, sw1, atB0, atB1);
            PROC_AG(n + 1, q10, sw0, atA0, atA1);
            PROC_AG(n + 1, q11, sw1, atB0, atB1);
        }
        {   // agent 38
            float q00[8], q01[8];
            loadA2(o0, s, 38, q00);
            loadA2(o1, s, 38, q01);
            PROC_AG(38, q00, sw0, atA0, atA1);
            PROC_AG(38, q01, sw1, atB0, atB1);
        }
    }

    // ============ head: 3 dense layers, intra-wave LDS exchange ============
#define HEAD_AND_OUT(AT0, AT1, ROWB)                                              \
    do {                                                                          \
        f32x4 x0 = AT0, x1 = AT1;                                                 \
        _Pragma("unroll")                                                         \
        for (int L = 0; L < 3; ++L) {                                             \
            const int unit = 114 + L * 2;                                         \
            const float* bias = (L == 0) ? b_ao : (L == 1) ? b_emb : b_out;       \
            const int N = (L == 2) ? 21 : 32;                                     \
            _Pragma("unroll")                                                     \
            for (int j = 0; j < 4; ++j) {                                         \
                const int row = s * 4 + j;                                        \
                __bf16 h0 = (__bf16)x0[j];                                        \
                hiw[row * 40 + cq] = h0;                                          \
                low[row * 40 + cq] = (__bf16)(x0[j] - (float)h0);                 \
                __bf16 h1 = (__bf16)x1[j];                                        \
                hiw[row * 40 + 16 + cq] = h1;                                     \
                low[row * 40 + 16 + cq] = (__bf16)(x1[j] - (float)h1);            \
            }                                                                     \
            bf16x8 ah = *(const bf16x8*)&hiw[cq * 40 + s * 8];                    \
            bf16x8 al = *(const bf16x8*)&low[cq * 40 + s * 8];                    \
            const bf16x8* bu = wf + (size_t)unit * 128;                           \
            f32x4 y0 = mm3(ah, al, bu[lane], bu[64 + lane], zf);                  \
            f32x4 y1 = mm3(ah, al, bu[128 + lane], bu[192 + lane], zf);           \
            const float bc0 = bias[cq];                                           \
            const float bc1 = (16 + cq < N) ? bias[16 + cq] : 0.f;                \
            _Pragma("unroll")                                                     \
            for (int j = 0; j < 4; ++j) {                                         \
                y0[j] += bc0;                                                     \
                y1[j] += bc1;                                                     \
                if (L < 2) { y0[j] = fmaxf(y0[j], 0.f); y1[j] = fmaxf(y1[j], 0.f); } \
            }                                                                     \
            x0 = y0; x1 = y1;                                                     \
        }                                                                         \
        _Pragma("unroll")                                                         \
        for (int j = 0; j < 4; ++j) {                                             \
            const int row = (ROWB) + s * 4 + j;                                   \
            out[(size_t)row * 21 + cq] = x0[j];                                   \
            if (cq < 5) out[(size_t)row * 21 + 16 + cq] = x1[j];                  \
        }                                                                         \
    } while (0)

    HEAD_AND_OUT(atA0, atA1, rowbase);
    HEAD_AND_OUT(atB0, atB1, rowbase + 16);
}

extern "C" void kernel_launch(void* const* d_in, const int* in_sizes, int n_in,
                              void* d_out, int out_size, void* d_ws, size_t ws_size,
                              hipStream_t stream) {
    const float* obs    = (const float*)d_in[0];
    const float* W_al   = (const float*)d_in[1];
    const float* b_al   = (const float*)d_in[2];
    const float* W_self = (const float*)d_in[3];
    const float* W_oth  = (const float*)d_in[5];
    const float* W_ao   = (const float*)d_in[7];
    const float* b_ao   = (const float*)d_in[8];
    const float* W_emb  = (const float*)d_in[9];
    const float* b_emb  = (const float*)d_in[10];
    const float* W_out  = (const float*)d_in[11];
    const float* b_out  = (const float*)d_in[12];
    float* out = (float*)d_out;
    bf16x8* ws = (bf16x8*)d_ws;

    prep_weights<<<120, 64, 0, stream>>>(W_al, W_self, W_oth, W_ao, W_emb, W_out, ws);

    const int B = in_sizes[0] / OBS;        // 65536
    qnet_fwd<<<B / 128, 256, 0, stream>>>(obs, b_al, b_ao, b_emb, b_out,
                                          (const bf16x8*)ws, out);
}

// Round 7
// 140.219 us; speedup vs baseline: 1.1562x; 1.1562x over previous
//
#include <hip/hip_runtime.h>

// QNet forward, MI355X — R7: everything-via-global_load_lds, counted vmcnt.
// B=65536 rows, obs=1129 (37 self + 39*28 others).
// 256 thr (4 waves), 64 rows/block (16/wave), grid 1024, 3 blocks/CU (45KB LDS).
//
// R6 post-mortem: per-CU outstanding-miss concurrency is the wall; VGPR-dest
// loads serialize on dependencies. R7 makes ALL streaming loads fire-and-forget:
//  - pass 1: A staged by 8 dword-glds/wave/chunk (per-lane swizzled src ->
//    linear LDS dest; ds_read_b128 readback, ~2-way banks), B by 2 dwordx4-glds.
//    Sync = s_waitcnt vmcnt(10) + s_barrier (never 0 in loop); A dbuf (own-wave,
//    lgkm-drained before overwrite), B triple-buffered (cross-wave).
//  - pass 2: W_oth re-padded to K=32 with LEADING zero row so agent slices
//    start at col 36+28n (16B-aligned grid); wave-private dbuf staging of
//    56-float pair windows via 16 dword-glds, vmcnt(16) sync, NO barriers.
// Swizzle: float f of row r stored at block (f>>2)^(r&7)  <=>  f = L^((i&7)<<2)
// per glds instr (verified identity).
//
// Fragment maps (gfx950 16x16x32 bf16): A/B: row|col = lane&15, k = 8*(lane>>4)+i
//   C/D: col = lane&15, row = 4*(lane>>4) + reg
// Split-bf16: 3-term logits/self/head, 2-term others.
//
// d_ws: 120 units of 128 bf16x8 (64 hi + 64 lo), 2KB each.
//   W_al: c*3+t | W_self: 108+c*2+t | W_oth'(K=32, row0=0,1..28=W,29..31=0): 112+t
//   W_ao: 114+t | W_emb: 116+t | W_out: 118+t

typedef __bf16 bf16x8 __attribute__((ext_vector_type(8)));
typedef float  f32x4  __attribute__((ext_vector_type(4)));

constexpr int OBS = 1129;

#define MFMA(a, b, c) __builtin_amdgcn_mfma_f32_16x16x32_bf16((a), (b), (c), 0, 0, 0)

__device__ __forceinline__ float4 ld4(const float* p) {
    float4 v;
    __builtin_memcpy(&v, p, 16);
    return v;
}

__device__ __forceinline__ void split8(const float* a, bf16x8& h, bf16x8& l) {
#pragma unroll
    for (int i = 0; i < 8; ++i) {
        __bf16 hb = (__bf16)a[i];
        h[i] = hb;
        l[i] = (__bf16)(a[i] - (float)hb);
    }
}

__device__ __forceinline__ f32x4 mm3(bf16x8 ah, bf16x8 al, bf16x8 bh, bf16x8 bl, f32x4 c) {
    c = MFMA(ah, bh, c);
    c = MFMA(ah, bl, c);
    c = MFMA(al, bh, c);
    return c;
}

__device__ __forceinline__ void glds16(const void* g, void* l) {
    __builtin_amdgcn_global_load_lds((const __attribute__((address_space(1))) void*)g,
                                     (__attribute__((address_space(3))) void*)l, 16, 0, 0);
}
__device__ __forceinline__ void glds4(const void* g, void* l) {
    __builtin_amdgcn_global_load_lds((const __attribute__((address_space(1))) void*)g,
                                     (__attribute__((address_space(3))) void*)l, 4, 0, 0);
}

// ---------------- prep: split weights into fragment order ----------------
__global__ void prep_weights(const float* __restrict__ W_al,
                             const float* __restrict__ W_self,
                             const float* __restrict__ W_oth,
                             const float* __restrict__ W_ao,
                             const float* __restrict__ W_emb,
                             const float* __restrict__ W_out,
                             bf16x8* __restrict__ ws)
{
    const int u = blockIdx.x;     // 120 units
    const int l = threadIdx.x;    // 64 lanes
    const int s = l >> 4, col = l & 15;
    const float* W; int K, N, ld, c, t, shift = 0;
    if (u < 108)      { c = u / 3;         t = u % 3;         W = W_al;   K = 1129; N = 40; ld = 40; }
    else if (u < 112) { c = (u - 108) / 2; t = (u - 108) & 1; W = W_self; K = 37;   N = 32; ld = 32; }
    else if (u < 114) { c = 0;             t = u - 112;       W = W_oth;  K = 28;   N = 32; ld = 32; shift = 1; }
    else if (u < 116) { c = 0;             t = u - 114;       W = W_ao;   K = 32;   N = 32; ld = 32; }
    else if (u < 118) { c = 0;             t = u - 116;       W = W_emb;  K = 32;   N = 32; ld = 32; }
    else              { c = 0;             t = u - 118;       W = W_out;  K = 32;   N = 21; ld = 21; }
    const int j = t * 16 + col;
    bf16x8 h, lo;
#pragma unroll
    for (int i = 0; i < 8; ++i) {
        int k = c * 32 + s * 8 + i;
        int kk = k - shift;
        float w = (kk >= 0 && kk < K && j < N) ? W[kk * ld + j] : 0.f;
        __bf16 hb = (__bf16)w;
        h[i]  = hb;
        lo[i] = (__bf16)(w - (float)hb);
    }
    ws[u * 128 + l]      = h;
    ws[u * 128 + 64 + l] = lo;
}

// ---------------- main kernel: 256 threads (4 waves), 64 rows ----------------
__global__ __launch_bounds__(256, 3)
void qnet_fwd(const float* __restrict__ obs,
              const float* __restrict__ b_al,
              const float* __restrict__ b_ao,
              const float* __restrict__ b_emb,
              const float* __restrict__ b_out,
              const bf16x8* __restrict__ wf,
              float* __restrict__ out)
{
    __shared__ __align__(16) char arena[34816]; // A dbuf 16384 | B tribuf 18432
    __shared__ float sW[4 * 656];               // per-wave att weights [16][41]

    const int t    = threadIdx.x;
    const int lane = t & 63;
    const int wv   = t >> 6;
    const int s    = lane >> 4;
    const int cq   = lane & 15;
    const int rowbase = blockIdx.x * 64 + wv * 16;
    const float* __restrict__ orow = obs + (size_t)(rowbase + cq) * OBS;
    const char* __restrict__ wfb = (const char*)wf;
    float* __restrict__ sWw = sW + wv * 656;

    const f32x4 zf = {0.f, 0.f, 0.f, 0.f};

    // -------- per-lane glds source indices (floats) --------
    unsigned aIdx[8];
#pragma unroll
    for (int i = 0; i < 8; ++i) {
        int r = 2 * i + (lane >> 5);
        unsigned f = (unsigned)((lane & 31) ^ ((r & 7) << 2));
        aIdx[i] = (unsigned)((rowbase + r) * OBS) + f;
    }
    // pass-1 ds-read offsets (within wave's 2KB A slice)
    const unsigned offA0 = (unsigned)(cq * 128 + (((2 * s)     ^ (cq & 7)) << 4));
    const unsigned offA1 = (unsigned)(cq * 128 + (((2 * s + 1) ^ (cq & 7)) << 4));

    char* aCur = arena + wv * 2048;
    char* aNxt = arena + 8192 + wv * 2048;
    char* pB0 = arena + 16384;
    char* pB1 = arena + 16384 + 6144;
    char* pB2 = arena + 16384 + 12288;

#define STAGE_A(DST, C)                                                           \
    do { _Pragma("unroll") for (int _i = 0; _i < 8; ++_i)                         \
        glds4(obs + aIdx[_i] + (C) * 32, (DST) + _i * 256); } while (0)
#define STAGE_BC(DST, C)                                                          \
    do { const char* _bs = wfb + (size_t)(C) * 6144;                              \
        glds16(_bs + wv * 1024 + lane * 16, (DST) + wv * 1024);                   \
        glds16(_bs + (4 + (wv & 1)) * 1024 + lane * 16,                           \
               (DST) + (4 + (wv & 1)) * 1024); } while (0)

    // ================= pass 1: logits = obs @ W_al =================
    f32x4 acc0 = zf, acc1 = zf, acc2 = zf;

    STAGE_A(aCur, 0); STAGE_BC(pB0, 0);
    STAGE_A(aNxt, 1); STAGE_BC(pB1, 1);

#define P1_MATH(FA0, FA1, BP)                                                     \
    do {                                                                          \
        float _av[8] = {(FA0).x, (FA0).y, (FA0).z, (FA0).w,                       \
                        (FA1).x, (FA1).y, (FA1).z, (FA1).w};                      \
        bf16x8 _ah, _al; split8(_av, _ah, _al);                                   \
        bf16x8 b0h = *(const bf16x8*)((BP) + lane * 16);                          \
        bf16x8 b0l = *(const bf16x8*)((BP) + 1024 + lane * 16);                   \
        bf16x8 b1h = *(const bf16x8*)((BP) + 2048 + lane * 16);                   \
        bf16x8 b1l = *(const bf16x8*)((BP) + 3072 + lane * 16);                   \
        bf16x8 b2h = *(const bf16x8*)((BP) + 4096 + lane * 16);                   \
        bf16x8 b2l = *(const bf16x8*)((BP) + 5120 + lane * 16);                   \
        __builtin_amdgcn_s_setprio(1);                                            \
        acc0 = mm3(_ah, _al, b0h, b0l, acc0);                                     \
        acc1 = mm3(_ah, _al, b1h, b1l, acc1);                                     \
        acc2 = mm3(_ah, _al, b2h, b2l, acc2);                                     \
        __builtin_amdgcn_s_setprio(0);                                            \
    } while (0)

    for (int c = 0; c <= 32; ++c) {
        asm volatile("s_waitcnt vmcnt(10)" ::: "memory");
        __builtin_amdgcn_s_barrier();
        __builtin_amdgcn_sched_barrier(0);
        float4 fa0 = *(const float4*)(aCur + offA0);
        float4 fa1 = *(const float4*)(aCur + offA1);
        asm volatile("s_waitcnt lgkmcnt(0)" ::: "memory");
        __builtin_amdgcn_sched_barrier(0);
        STAGE_A(aCur, c + 2);                // overwrites A(c) slice (drained)
        STAGE_BC(pB2, c + 2);                // overwrites B(c-1) (readers done)
        P1_MATH(fa0, fa1, pB0);
        char* tA = aCur; aCur = aNxt; aNxt = tA;
        char* tB = pB0; pB0 = pB1; pB1 = pB2; pB2 = tB;
    }
    {   // c = 33: stage only B(35)
        asm volatile("s_waitcnt vmcnt(10)" ::: "memory");
        __builtin_amdgcn_s_barrier();
        __builtin_amdgcn_sched_barrier(0);
        float4 fa0 = *(const float4*)(aCur + offA0);
        float4 fa1 = *(const float4*)(aCur + offA1);
        STAGE_BC(pB2, 35);
        P1_MATH(fa0, fa1, pB0);
        char* tA = aCur; aCur = aNxt; aNxt = tA;
        char* tB = pB0; pB0 = pB1; pB1 = pB2; pB2 = tB;
    }
    {   // c = 34
        asm volatile("s_waitcnt vmcnt(2)" ::: "memory");
        __builtin_amdgcn_s_barrier();
        __builtin_amdgcn_sched_barrier(0);
        float4 fa0 = *(const float4*)(aCur + offA0);
        float4 fa1 = *(const float4*)(aCur + offA1);
        P1_MATH(fa0, fa1, pB0);
        char* tB = pB0; pB0 = pB1; pB1 = pB2; pB2 = tB;
    }
    {   // c = 35: masked A tail via VGPR loads
        asm volatile("s_waitcnt vmcnt(0)" ::: "memory");
        __builtin_amdgcn_s_barrier();
        __builtin_amdgcn_sched_barrier(0);
        float av[8] = {0, 0, 0, 0, 0, 0, 0, 0};
        if (s == 0) {
            float4 p = ld4(orow + 1120), q = ld4(orow + 1124);
            av[0] = p.x; av[1] = p.y; av[2] = p.z; av[3] = p.w;
            av[4] = q.x; av[5] = q.y; av[6] = q.z; av[7] = q.w;
        } else if (s == 1) {
            av[0] = orow[1128];
        }
        float4 fa0 = {av[0], av[1], av[2], av[3]};
        float4 fa1 = {av[4], av[5], av[6], av[7]};
        P1_MATH(fa0, fa1, pB0);
    }
    __syncthreads();   // arena handoff to pass 2 (everything drained anyway)

    // ===== softmax over 40 cols (intra-wave; C rows: row = 4s+j) =====
    {
        const float bal0 = b_al[cq];
        const float bal1 = b_al[16 + cq];
        const bool  v2m  = (cq < 8);
        const float bal2 = v2m ? b_al[32 + cq] : 0.f;
#pragma unroll
        for (int j = 0; j < 4; ++j) {
            float v0 = acc0[j] + bal0, v1 = acc1[j] + bal1, vv = acc2[j] + bal2;
            float m = fmaxf(fmaxf(v0, v1), v2m ? vv : -3.4e38f);
#pragma unroll
            for (int d = 1; d < 16; d <<= 1) m = fmaxf(m, __shfl_xor(m, d));
            float e0 = __expf(v0 - m), e1 = __expf(v1 - m);
            float e2 = v2m ? __expf(vv - m) : 0.f;
            float sm = e0 + e1 + e2;
#pragma unroll
            for (int d = 1; d < 16; d <<= 1) sm += __shfl_xor(sm, d);
            float inv = 1.f / sm;
            const int row = s * 4 + j;
            sWw[row * 41 + cq]      = e0 * inv;
            sWw[row * 41 + 16 + cq] = e1 * inv;
            if (v2m) sWw[row * 41 + 32 + cq] = e2 * inv;
        }
    }
    // no barrier: sWw wave-private

    // ================= pass 2: encodings, weighted sum =================
    const bf16x8* bo = wf + (size_t)112 * 128;
    const bf16x8 Boh0 = bo[lane],       Bol0 = bo[64 + lane];
    const bf16x8 Boh1 = bo[128 + lane], Bol1 = bo[192 + lane];

    f32x4 at0 = zf, at1 = zf;
    {   // self encoding (no relu), 3-term, weight att_w[row][0]
        f32x4 e0 = zf, e1 = zf;
        {
            float4 p = ld4(orow + s * 8), q = ld4(orow + s * 8 + 4);
            float av[8] = {p.x, p.y, p.z, p.w, q.x, q.y, q.z, q.w};
            bf16x8 ah, al; split8(av, ah, al);
            const bf16x8* bu = wf + (size_t)108 * 128;
            e0 = mm3(ah, al, bu[lane],       bu[64 + lane],  e0);
            e1 = mm3(ah, al, bu[128 + lane], bu[192 + lane], e1);
        }
        {
            float av[8] = {0, 0, 0, 0, 0, 0, 0, 0};
            if (s == 0) {
                float4 p = ld4(orow + 32);
                av[0] = p.x; av[1] = p.y; av[2] = p.z; av[3] = p.w;
                av[4] = orow[36];
            }
            bf16x8 ah, al; split8(av, ah, al);
            const bf16x8* bu = wf + (size_t)110 * 128;
            e0 = mm3(ah, al, bu[lane],       bu[64 + lane],  e0);
            e1 = mm3(ah, al, bu[128 + lane], bu[192 + lane], e1);
        }
#pragma unroll
        for (int j = 0; j < 4; ++j) {
            float w0 = sWw[(s * 4 + j) * 41];
            at0[j] = w0 * e0[j];
            at1[j] = w0 * e1[j];
        }
    }

    // ---- other agents 0..37 via wave-private glds dbuf staging ----
    asm volatile("s_waitcnt vmcnt(0)" ::: "memory");   // clean slate for counting

    unsigned pIdx[16];
#pragma unroll
    for (int i = 0; i < 16; ++i) {
        unsigned f = (unsigned)(lane ^ ((i & 7) << 2));
        pIdx[i] = (unsigned)((rowbase + i) * OBS) + 36u + f;
    }
#define STAGE_P(DST, P)                                                           \
    do { _Pragma("unroll") for (int _i = 0; _i < 16; ++_i)                        \
        glds4(obs + pIdx[_i] + (P) * 56, (DST) + _i * 256); } while (0)

    // read offsets: agent a2, halves h: block (a2*7+2s+h)^(cq&7)
    const unsigned oP00 = (unsigned)(cq * 256 + (((2 * s)     ^ (cq & 7)) << 4));
    const unsigned oP01 = (unsigned)(cq * 256 + (((2 * s + 1) ^ (cq & 7)) << 4));
    const unsigned oP10 = (unsigned)(cq * 256 + (((7 + 2 * s) ^ (cq & 7)) << 4));
    const unsigned oP11 = (unsigned)(cq * 256 + (((8 + 2 * s) ^ (cq & 7)) << 4));

    char* q0 = arena + wv * 8192;
    char* q1 = q0 + 4096;
    STAGE_P(q0, 0);
    STAGE_P(q1, 1);

#define PROC2(N, U0, U1)                                                          \
    do {                                                                          \
        bf16x8 _ah;                                                               \
        _ah[0] = (__bf16)(U0).x; _ah[1] = (__bf16)(U0).y;                         \
        _ah[2] = (__bf16)(U0).z; _ah[3] = (__bf16)(U0).w;                         \
        _ah[4] = (__bf16)(U1).x; _ah[5] = (__bf16)(U1).y;                         \
        _ah[6] = (__bf16)(U1).z; _ah[7] = (__bf16)(U1).w;                         \
        f32x4 _e0 = MFMA(_ah, Boh0, zf); _e0 = MFMA(_ah, Bol0, _e0);              \
        f32x4 _e1 = MFMA(_ah, Boh1, zf); _e1 = MFMA(_ah, Bol1, _e1);              \
        _Pragma("unroll")                                                         \
        for (int _j = 0; _j < 4; ++_j) {                                          \
            float _wn = sWw[(s * 4 + _j) * 41 + 1 + (N)];                         \
            at0[_j] += _wn * fmaxf(_e0[_j], 0.f);                                 \
            at1[_j] += _wn * fmaxf(_e1[_j], 0.f);                                 \
        }                                                                         \
    } while (0)

    for (int p = 0; p <= 16; ++p) {
        asm volatile("s_waitcnt vmcnt(16)" ::: "memory");
        __builtin_amdgcn_sched_barrier(0);
        float4 u00 = *(const float4*)(q0 + oP00);
        float4 u01 = *(const float4*)(q0 + oP01);
        float4 u10 = *(const float4*)(q0 + oP10);
        float4 u11 = *(const float4*)(q0 + oP11);
        asm volatile("s_waitcnt lgkmcnt(0)" ::: "memory");
        __builtin_amdgcn_sched_barrier(0);
        STAGE_P(q0, p + 2);                   // overwrite own drained buf
        __builtin_amdgcn_s_setprio(1);
        PROC2(2 * p,     u00, u01);
        PROC2(2 * p + 1, u10, u11);
        __builtin_amdgcn_s_setprio(0);
        char* tq = q0; q0 = q1; q1 = tq;
    }
    {   // p = 17
        asm volatile("s_waitcnt vmcnt(16)" ::: "memory");
        __builtin_amdgcn_sched_barrier(0);
        float4 u00 = *(const float4*)(q0 + oP00);
        float4 u01 = *(const float4*)(q0 + oP01);
        float4 u10 = *(const float4*)(q0 + oP10);
        float4 u11 = *(const float4*)(q0 + oP11);
        PROC2(34, u00, u01);
        PROC2(35, u10, u11);
        char* tq = q0; q0 = q1; q1 = tq;
    }
    {   // p = 18
        asm volatile("s_waitcnt vmcnt(0)" ::: "memory");
        __builtin_amdgcn_sched_barrier(0);
        float4 u00 = *(const float4*)(q0 + oP00);
        float4 u01 = *(const float4*)(q0 + oP01);
        float4 u10 = *(const float4*)(q0 + oP10);
        float4 u11 = *(const float4*)(q0 + oP11);
        PROC2(36, u00, u01);
        PROC2(37, u10, u11);
    }
    {   // agent 38 via VGPR loads, virtual-k alignment (B' has leading zero row)
        const float* op = orow + 1100;        // col 36 + 28*38
        float av[8];
        if (s < 3) {
            float4 p = ld4(op + s * 8), q = ld4(op + s * 8 + 4);
            av[0] = p.x; av[1] = p.y; av[2] = p.z; av[3] = p.w;
            av[4] = q.x; av[5] = q.y; av[6] = q.z; av[7] = q.w;
        } else {
            float4 p = ld4(op + 24);
            av[0] = p.x; av[1] = p.y; av[2] = p.z; av[3] = p.w;
            av[4] = op[28];
            av[5] = 0.f; av[6] = 0.f; av[7] = 0.f;
        }
        float4 u0 = {av[0], av[1], av[2], av[3]};
        float4 u1 = {av[4], av[5], av[6], av[7]};
        PROC2(38, u0, u1);
    }

    // ============ head: 3 dense layers, wave-private LDS (arena reuse) ============
    __bf16* hiw = (__bf16*)(arena + wv * 8192);
    __bf16* low = hiw + 640;
    f32x4 x0 = at0, x1 = at1;
#pragma unroll
    for (int L = 0; L < 3; ++L) {
        const int unit = 114 + L * 2;
        const float* bias = (L == 0) ? b_ao : (L == 1) ? b_emb : b_out;
        const int N = (L == 2) ? 21 : 32;
#pragma unroll
        for (int j = 0; j < 4; ++j) {
            const int row = s * 4 + j;
            __bf16 h0 = (__bf16)x0[j];
            hiw[row * 40 + cq] = h0;
            low[row * 40 + cq] = (__bf16)(x0[j] - (float)h0);
            __bf16 h1 = (__bf16)x1[j];
            hiw[row * 40 + 16 + cq] = h1;
            low[row * 40 + 16 + cq] = (__bf16)(x1[j] - (float)h1);
        }
        bf16x8 ah = *(const bf16x8*)&hiw[cq * 40 + s * 8];
        bf16x8 al = *(const bf16x8*)&low[cq * 40 + s * 8];
        const bf16x8* bu = wf + (size_t)unit * 128;
        f32x4 y0 = mm3(ah, al, bu[lane],       bu[64 + lane],  zf);
        f32x4 y1 = mm3(ah, al, bu[128 + lane], bu[192 + lane], zf);
        const float bc0 = bias[cq];
        const float bc1 = (16 + cq < N) ? bias[16 + cq] : 0.f;
#pragma unroll
        for (int j = 0; j < 4; ++j) {
            y0[j] += bc0;
            y1[j] += bc1;
            if (L < 2) { y0[j] = fmaxf(y0[j], 0.f); y1[j] = fmaxf(y1[j], 0.f); }
        }
        x0 = y0; x1 = y1;
    }

#pragma unroll
    for (int j = 0; j < 4; ++j) {
        const int row = rowbase + s * 4 + j;
        out[(size_t)row * 21 + cq] = x0[j];
        if (cq < 5) out[(size_t)row * 21 + 16 + cq] = x1[j];
    }
}

extern "C" void kernel_launch(void* const* d_in, const int* in_sizes, int n_in,
                              void* d_out, int out_size, void* d_ws, size_t ws_size,
                              hipStream_t stream) {
    const float* obs    = (const float*)d_in[0];
    const float* W_al   = (const float*)d_in[1];
    const float* b_al   = (const float*)d_in[2];
    const float* W_self = (const float*)d_in[3];
    const float* W_oth  = (const float*)d_in[5];
    const float* W_ao   = (const float*)d_in[7];
    const float* b_ao   = (const float*)d_in[8];
    const float* W_emb  = (const float*)d_in[9];
    const float* b_emb  = (const float*)d_in[10];
    const float* W_out  = (const float*)d_in[11];
    const float* b_out  = (const float*)d_in[12];
    float* out = (float*)d_out;
    bf16x8* ws = (bf16x8*)d_ws;

    prep_weights<<<120, 64, 0, stream>>>(W_al, W_self, W_oth, W_ao, W_emb, W_out, ws);

    const int B = in_sizes[0] / OBS;        // 65536
    qnet_fwd<<<B / 64, 256, 0, stream>>>(obs, b_al, b_ao, b_emb, b_out,
                                         (const bf16x8*)ws, out);
}